// Round 5
// baseline (2095.879 us; speedup 1.0000x reference)
//
#include <hip/hip_runtime.h>
#include <hip/hip_bf16.h>

#define D 128
#define BM 64
#define BK 32
#define XS 66        // padded LDS stride for transposed x tile (gemm)
#define RNG 16384    // out-degree histogram range size (64 KB LDS of int counters)
#define ODCH 8       // out-degree edge chunks
#define EPB 16384    // edges per partition block (1024 thr x 16)
#define NBMAX 1024   // max dst buckets (N <= 131072)

__device__ __forceinline__ float bf2f(unsigned int v) {
    union { unsigned int u; float f; } t;
    t.u = v << 16;
    return t.f;
}

__device__ __forceinline__ const int* sel3(int r, const int* a, const int* b, const int* c) {
    return (r == 0) ? a : (r == 1) ? b : c;
}

// ---- out-degree: chunked LDS-private histograms, atomic-free at global ----
__global__ __launch_bounds__(256) void outdeg_hist(const int* __restrict__ s0,
                                                   const int* __restrict__ s1,
                                                   const int* __restrict__ s2,
                                                   int* __restrict__ scratch,
                                                   int N, int E, int chunkE, int Npad) {
    __shared__ int h[RNG];
    const int chunk = blockIdx.x;   // 0..ODCH-1
    const int range = blockIdx.y;   // 0..NR-1
    const int rel   = blockIdx.z;
    const int* src = sel3(rel, s0, s1, s2);
    const int tid = threadIdx.x;
    for (int i = tid; i < RNG; i += 256) h[i] = 0;
    __syncthreads();
    const int base = chunk * chunkE;
    const int end  = min(E, base + chunkE);
    for (int i = base + tid; i < end; i += 256) {
        int v = src[i];
        if ((v >> 14) == range) atomicAdd(&h[v & (RNG - 1)], 1);  // LDS atomic
    }
    __syncthreads();
    int* dp = scratch + ((size_t)(rel * ODCH + chunk)) * Npad + ((size_t)range << 14);
    for (int i = tid; i < RNG; i += 256) dp[i] = h[i];
}

__global__ void outdeg_reduce(const int* __restrict__ scratch, float* __restrict__ rs_out,
                              int N, int Npad) {
    int rel = blockIdx.y;
    int n = blockIdx.x * blockDim.x + threadIdx.x;
    if (n >= N) return;
    int s = 0;
#pragma unroll
    for (int c = 0; c < ODCH; ++c) s += scratch[((size_t)(rel * ODCH + c)) * Npad + n];
    rs_out[(size_t)rel * N + n] = rsqrtf(fmaxf((float)s, 1.0f));
}

// ---- partition pass 1: per-(bucket,chunk) counts, non-atomic global writes ----
__global__ __launch_bounds__(1024) void part_count(const int* __restrict__ d0,
                                                   const int* __restrict__ d1,
                                                   const int* __restrict__ d2,
                                                   int* __restrict__ offs,
                                                   int E, int NB, int NCH, int M) {
    __shared__ int hist[NBMAX];
    const int chunk = blockIdx.x;
    const int rel   = blockIdx.y;
    const int* dst = sel3(rel, d0, d1, d2);
    const int tid = threadIdx.x;
    hist[tid] = 0;                       // blockDim 1024 == NBMAX
    __syncthreads();
    const int base = chunk * EPB;
    const int end  = min(E, base + EPB);
    for (int i = base + tid; i < end; i += 1024)
        atomicAdd(&hist[dst[i] >> 7], 1);   // LDS atomic
    __syncthreads();
    int* offs_r = offs + (size_t)rel * M;
    for (int b = tid; b < NB; b += 1024) offs_r[b * NCH + chunk] = hist[b];
}

// ---- partition pass 2: exclusive scan over [bucket][chunk], one block per relation ----
__global__ __launch_bounds__(1024) void part_scan(int* __restrict__ offs, int M) {
    __shared__ int bs[1024];
    const int tid = threadIdx.x;
    int* a = offs + (size_t)blockIdx.x * M;
    const int PT = (M + 1023) >> 10;
    const int i0 = tid * PT;
    int s = 0;
    for (int j = 0; j < PT; ++j) {
        int idx = i0 + j;
        if (idx < M) s += a[idx];
    }
    bs[tid] = s;
    __syncthreads();
    for (int o = 1; o < 1024; o <<= 1) {
        int t = (tid >= o) ? bs[tid - o] : 0;
        __syncthreads();
        bs[tid] += t;
        __syncthreads();
    }
    int run = bs[tid] - s;   // exclusive base for this thread's range
    for (int j = 0; j < PT; ++j) {
        int idx = i0 + j;
        if (idx < M) {
            int t = a[idx];
            a[idx] = run;
            run += t;
        }
    }
}

// ---- partition pass 3: scatter packed (src<<7)|(dst&127), LDS cursors only ----
__global__ __launch_bounds__(1024) void part_scatter(const int* __restrict__ s0,
                                                     const int* __restrict__ d0,
                                                     const int* __restrict__ s1,
                                                     const int* __restrict__ d1,
                                                     const int* __restrict__ s2,
                                                     const int* __restrict__ d2,
                                                     const int* __restrict__ offs,
                                                     int* __restrict__ edges,
                                                     int E, int NB, int NCH, int M) {
    __shared__ int cur[NBMAX];
    const int chunk = blockIdx.x;
    const int rel   = blockIdx.y;
    const int* src = sel3(rel, s0, s1, s2);
    const int* dst = sel3(rel, d0, d1, d2);
    const int tid = threadIdx.x;
    const int* offs_r = offs + (size_t)rel * M;
    for (int b = tid; b < NB; b += 1024) cur[b] = offs_r[b * NCH + chunk];
    __syncthreads();
    int* edges_r = edges + (size_t)rel * E;
    const int base = chunk * EPB;
    const int end  = min(E, base + EPB);
    for (int i = base + tid; i < end; i += 1024) {
        int d = dst[i];
        int idx = atomicAdd(&cur[d >> 7], 1);   // LDS atomic, returns rank
        edges_r[idx] = (src[i] << 7) | (d & 127);
    }
}

// ---- y = rs_out[row] * (x @ W)  (fp32 compute, bf16 store) ----
__global__ __launch_bounds__(256) void gemm_kernel(const float* __restrict__ x,
                                                   const float* __restrict__ W,
                                                   const float* __restrict__ rs_out,
                                                   __hip_bfloat16* __restrict__ y, int nrows) {
    __shared__ float xs[BK * XS];
    __shared__ float ws[BK][D];

    const int tid = threadIdx.x;
    const int tx = tid & 31;
    const int ty = tid >> 5;
    const int row0 = blockIdx.x * BM;

    const int xr0 = tid >> 3;
    const int xk4 = tid & 7;
    const int wk0 = tid >> 5;
    const int wc4 = tid & 31;

    float acc[8][4];
#pragma unroll
    for (int i = 0; i < 8; ++i)
#pragma unroll
        for (int j = 0; j < 4; ++j) acc[i][j] = 0.f;

    float4 xv[2];
    float4 wv4[4];

#pragma unroll
    for (int l = 0; l < 2; ++l) {
        int grow = row0 + xr0 + l * 32;
        xv[l] = (grow < nrows) ? *(const float4*)(x + (size_t)grow * D + xk4 * 4)
                               : make_float4(0.f, 0.f, 0.f, 0.f);
    }
#pragma unroll
    for (int l = 0; l < 4; ++l)
        wv4[l] = *(const float4*)(W + (size_t)(wk0 + l * 8) * D + wc4 * 4);

    for (int kt = 0; kt < D; kt += BK) {
        __syncthreads();
#pragma unroll
        for (int l = 0; l < 2; ++l) {
            int r = xr0 + l * 32;
            xs[(xk4 * 4 + 0) * XS + r] = xv[l].x;
            xs[(xk4 * 4 + 1) * XS + r] = xv[l].y;
            xs[(xk4 * 4 + 2) * XS + r] = xv[l].z;
            xs[(xk4 * 4 + 3) * XS + r] = xv[l].w;
        }
#pragma unroll
        for (int l = 0; l < 4; ++l)
            *(float4*)&ws[wk0 + l * 8][wc4 * 4] = wv4[l];
        __syncthreads();
        if (kt + BK < D) {
            int ktn = kt + BK;
#pragma unroll
            for (int l = 0; l < 2; ++l) {
                int grow = row0 + xr0 + l * 32;
                xv[l] = (grow < nrows) ? *(const float4*)(x + (size_t)grow * D + ktn + xk4 * 4)
                                       : make_float4(0.f, 0.f, 0.f, 0.f);
            }
#pragma unroll
            for (int l = 0; l < 4; ++l)
                wv4[l] = *(const float4*)(W + (size_t)(ktn + wk0 + l * 8) * D + wc4 * 4);
        }
#pragma unroll
        for (int k = 0; k < BK; ++k) {
            float4 wv = *(const float4*)&ws[k][tx * 4];
            const float* xr = &xs[k * XS + ty * 8];
            float2 p0 = *(const float2*)(xr);
            float2 p1 = *(const float2*)(xr + 2);
            float2 p2 = *(const float2*)(xr + 4);
            float2 p3 = *(const float2*)(xr + 6);
            float xv8[8] = {p0.x, p0.y, p1.x, p1.y, p2.x, p2.y, p3.x, p3.y};
#pragma unroll
            for (int i = 0; i < 8; ++i) {
                acc[i][0] += xv8[i] * wv.x;
                acc[i][1] += xv8[i] * wv.y;
                acc[i][2] += xv8[i] * wv.z;
                acc[i][3] += xv8[i] * wv.w;
            }
        }
    }
#pragma unroll
    for (int i = 0; i < 8; ++i) {
        int grow = row0 + ty * 8 + i;
        if (grow < nrows) {
            float s = rs_out[grow];
            union { ushort4 u; __hip_bfloat16 h[4]; } pk;
            pk.h[0] = __float2bfloat16(acc[i][0] * s);
            pk.h[1] = __float2bfloat16(acc[i][1] * s);
            pk.h[2] = __float2bfloat16(acc[i][2] * s);
            pk.h[3] = __float2bfloat16(acc[i][3] * s);
            *(ushort4*)((unsigned short*)y + (size_t)grow * D + tx * 4) = pk.u;
        }
    }
}

// ---- bucket aggregate: one block per 128-node dst bucket, LDS f32 accumulator ----
// MODE 0: out = acc   1: out += acc   2: out = relu(out + acc + b0+b1+b2)
template <int MODE>
__global__ __launch_bounds__(256) void agg_bucket(const unsigned short* __restrict__ y,
                                                  const int* __restrict__ edges,
                                                  const int* __restrict__ offs,
                                                  const float* __restrict__ b0,
                                                  const float* __restrict__ b1,
                                                  const float* __restrict__ b2,
                                                  float* __restrict__ out,
                                                  int N, int E, int NB, int NCH) {
    __shared__ float acc[128 * D];   // 64 KB
    __shared__ int hist[128];
    __shared__ float rsl[128];
    const int tid = threadIdx.x;
    const int bkt = blockIdx.x;
    const int j0 = offs[bkt * NCH];
    const int j1 = (bkt == NB - 1) ? E : offs[(bkt + 1) * NCH];

    if (tid < 128) hist[tid] = 0;
    float4* a4 = (float4*)acc;
    for (int i = tid; i < 128 * D / 4; i += 256) a4[i] = make_float4(0.f, 0.f, 0.f, 0.f);
    __syncthreads();
    // in-degree histogram of this bucket
    for (int j = j0 + tid; j < j1; j += 256) atomicAdd(&hist[edges[j] & 127], 1);
    __syncthreads();
    if (tid < 128) rsl[tid] = rsqrtf(fmaxf((float)hist[tid], 1.0f));
    __syncthreads();
    // accumulate: one edge per wave64; lane covers dims (2l, 2l+1)
    const int wave = tid >> 6;
    const int lane = tid & 63;
    for (int j = j0 + wave; j < j1; j += 4) {
        int pk = edges[j];              // uniform per wave
        int s  = pk >> 7;
        int dl = pk & 127;
        float c = rsl[dl];
        unsigned int u = ((const unsigned int*)(y + (size_t)s * D))[lane];
        atomicAdd(&acc[dl * D + 2 * lane],     c * bf2f(u & 0xffffu));
        atomicAdd(&acc[dl * D + 2 * lane + 1], c * bf2f(u >> 16));
    }
    __syncthreads();
    // epilogue: write 128 rows once
    const int node0 = bkt * 128;
    for (int q = tid; q < 128 * D / 4; q += 256) {
        int dl = q >> 5;
        int d4 = q & 31;
        int node = node0 + dl;
        if (node >= N) break;   // q monotone -> node monotone
        float4 v = a4[q];
        float* orow = out + (size_t)node * D + d4 * 4;
        if (MODE == 0) {
            *(float4*)orow = v;
        } else {
            float4 p = *(const float4*)orow;
            v.x += p.x; v.y += p.y; v.z += p.z; v.w += p.w;
            if (MODE == 2) {
                int c0 = d4 * 4;
                v.x = fmaxf(v.x + b0[c0 + 0] + b1[c0 + 0] + b2[c0 + 0], 0.f);
                v.y = fmaxf(v.y + b0[c0 + 1] + b1[c0 + 1] + b2[c0 + 1], 0.f);
                v.z = fmaxf(v.z + b0[c0 + 2] + b1[c0 + 2] + b2[c0 + 2], 0.f);
                v.w = fmaxf(v.w + b0[c0 + 3] + b1[c0 + 3] + b2[c0 + 3], 0.f);
            }
            *(float4*)orow = v;
        }
    }
}

extern "C" void kernel_launch(void* const* d_in, const int* in_sizes, int n_in,
                              void* d_out, int out_size, void* d_ws, size_t ws_size,
                              hipStream_t stream) {
    const float* x = (const float*)d_in[0];
    const float* W[3]   = {(const float*)d_in[1], (const float*)d_in[5], (const float*)d_in[9]};
    const float* b[3]   = {(const float*)d_in[2], (const float*)d_in[6], (const float*)d_in[10]};
    const int*   src[3] = {(const int*)d_in[3],   (const int*)d_in[7],   (const int*)d_in[11]};
    const int*   dst[3] = {(const int*)d_in[4],   (const int*)d_in[8],   (const int*)d_in[12]};

    const int N = in_sizes[0] / D;
    const int E = in_sizes[3];
    float* out = (float*)d_out;

    const int NR    = (N + RNG - 1) / RNG;        // out-degree ranges (7)
    const int Npad  = NR * RNG;                   // 114688
    const int chunkE = (E + ODCH - 1) / ODCH;     // 75000
    const int NB    = (N + 127) >> 7;             // dst buckets (782)
    const int NCH   = (E + EPB - 1) / EPB;        // partition chunks (37)
    const int M     = NB * NCH;                   // offs elements per relation

    // ws: [rs_out 3N f][odscratch 3*ODCH*Npad i][offs 3M i][edges 3E i][y N*D bf16] ~45 MB
    char* p = (char*)d_ws;
    auto align16 = [](char* q) { return (char*)(((uintptr_t)q + 15) & ~(uintptr_t)15); };
    float* rs_out = (float*)p;      p = align16(p + (size_t)3 * N * 4);
    int* odscr    = (int*)p;        p = align16(p + (size_t)3 * ODCH * Npad * 4);
    int* offs     = (int*)p;        p = align16(p + (size_t)3 * M * 4);
    int* edges    = (int*)p;        p = align16(p + (size_t)3 * E * 4);
    unsigned short* y = (unsigned short*)p;

    // out-degree -> rs_out (atomic-free at global)
    outdeg_hist<<<dim3(ODCH, NR, 3), 256, 0, stream>>>(src[0], src[1], src[2],
                                                       odscr, N, E, chunkE, Npad);
    outdeg_reduce<<<dim3((N + 255) / 256, 3), 256, 0, stream>>>(odscr, rs_out, N, Npad);

    // dst-bucket partition (atomic-free at global)
    part_count<<<dim3(NCH, 3), 1024, 0, stream>>>(dst[0], dst[1], dst[2], offs, E, NB, NCH, M);
    part_scan<<<3, 1024, 0, stream>>>(offs, M);
    part_scatter<<<dim3(NCH, 3), 1024, 0, stream>>>(src[0], dst[0], src[1], dst[1],
                                                    src[2], dst[2], offs, edges, E, NB, NCH, M);

    const int gblocks = (N + BM - 1) / BM;
    for (int r = 0; r < 3; ++r) {
        gemm_kernel<<<gblocks, 256, 0, stream>>>(x, W[r], rs_out + (size_t)r * N,
                                                 (__hip_bfloat16*)y, N);
        const int* offs_r  = offs + (size_t)r * M;
        const int* edges_r = edges + (size_t)r * E;
        if (r == 0)
            agg_bucket<0><<<NB, 256, 0, stream>>>(y, edges_r, offs_r, b[0], b[1], b[2],
                                                  out, N, E, NB, NCH);
        else if (r == 1)
            agg_bucket<1><<<NB, 256, 0, stream>>>(y, edges_r, offs_r, b[0], b[1], b[2],
                                                  out, N, E, NB, NCH);
        else
            agg_bucket<2><<<NB, 256, 0, stream>>>(y, edges_r, offs_r, b[0], b[1], b[2],
                                                  out, N, E, NB, NCH);
    }
}

// Round 6
// 771.454 us; speedup vs baseline: 2.7168x; 2.7168x over previous
//
#include <hip/hip_runtime.h>
#include <hip/hip_bf16.h>

#define D 128
#define BM 64
#define BK 32
#define XS 66        // padded LDS stride for transposed x tile (gemm)
#define RNG 8192     // out-degree histogram range size (32 KB LDS)
#define RSH 13       // log2(RNG)
#define ODCH 4       // out-degree edge chunks
#define EPB 16384    // edges per partition block (1024 thr x 16)
#define NBMAX 1024   // max dst buckets (N <= 131072)

__device__ __forceinline__ float bf2f(unsigned short v) {
    union { unsigned int u; float f; } t;
    t.u = ((unsigned int)v) << 16;
    return t.f;
}

__device__ __forceinline__ const int* sel3(int r, const int* a, const int* b, const int* c) {
    return (r == 0) ? a : (r == 1) ? b : c;
}

// ---- out-degree: chunked LDS-private histograms, atomic-free at global ----
__global__ __launch_bounds__(256) void outdeg_hist(const int* __restrict__ s0,
                                                   const int* __restrict__ s1,
                                                   const int* __restrict__ s2,
                                                   int* __restrict__ scratch,
                                                   int E, int chunkE, int Npad) {
    __shared__ int h[RNG];
    const int chunk = blockIdx.x;   // 0..ODCH-1
    const int range = blockIdx.y;   // 0..NR-1
    const int rel   = blockIdx.z;
    const int* src = sel3(rel, s0, s1, s2);
    const int tid = threadIdx.x;
    for (int i = tid; i < RNG; i += 256) h[i] = 0;
    __syncthreads();
    const int base = chunk * chunkE;
    const int end  = min(E, base + chunkE);
    for (int i = base + tid; i < end; i += 256) {
        int v = src[i];
        if ((v >> RSH) == range) atomicAdd(&h[v & (RNG - 1)], 1);  // LDS atomic
    }
    __syncthreads();
    int* dp = scratch + ((size_t)(rel * ODCH + chunk)) * Npad + ((size_t)range << RSH);
    for (int i = tid; i < RNG; i += 256) dp[i] = h[i];
}

__global__ void outdeg_reduce(const int* __restrict__ scratch, float* __restrict__ rs_out,
                              int N, int Npad) {
    int rel = blockIdx.y;
    int n = blockIdx.x * blockDim.x + threadIdx.x;
    if (n >= N) return;
    int s = 0;
#pragma unroll
    for (int c = 0; c < ODCH; ++c) s += scratch[((size_t)(rel * ODCH + c)) * Npad + n];
    rs_out[(size_t)rel * N + n] = rsqrtf(fmaxf((float)s, 1.0f));
}

// ---- partition pass 1: per-(bucket,chunk) counts, non-atomic global writes ----
__global__ __launch_bounds__(1024) void part_count(const int* __restrict__ d0,
                                                   const int* __restrict__ d1,
                                                   const int* __restrict__ d2,
                                                   int* __restrict__ offs,
                                                   int E, int NB, int NCH, int M) {
    __shared__ int hist[NBMAX];
    const int chunk = blockIdx.x;
    const int rel   = blockIdx.y;
    const int* dst = sel3(rel, d0, d1, d2);
    const int tid = threadIdx.x;
    hist[tid] = 0;
    __syncthreads();
    const int base = chunk * EPB;
    const int end  = min(E, base + EPB);
    for (int i = base + tid; i < end; i += 1024)
        atomicAdd(&hist[dst[i] >> 7], 1);   // LDS atomic
    __syncthreads();
    int* offs_r = offs + (size_t)rel * M;
    for (int b = tid; b < NB; b += 1024) offs_r[b * NCH + chunk] = hist[b];
}

// ---- partition pass 2: exclusive scan over [bucket][chunk], one block per relation ----
__global__ __launch_bounds__(1024) void part_scan(int* __restrict__ offs, int M) {
    __shared__ int bs[1024];
    const int tid = threadIdx.x;
    int* a = offs + (size_t)blockIdx.x * M;
    const int PT = (M + 1023) >> 10;
    const int i0 = tid * PT;
    int s = 0;
    for (int j = 0; j < PT; ++j) {
        int idx = i0 + j;
        if (idx < M) s += a[idx];
    }
    bs[tid] = s;
    __syncthreads();
    for (int o = 1; o < 1024; o <<= 1) {
        int t = (tid >= o) ? bs[tid - o] : 0;
        __syncthreads();
        bs[tid] += t;
        __syncthreads();
    }
    int run = bs[tid] - s;
    for (int j = 0; j < PT; ++j) {
        int idx = i0 + j;
        if (idx < M) {
            int t = a[idx];
            a[idx] = run;
            run += t;
        }
    }
}

// ---- partition pass 3: scatter packed (src<<7)|(dst&127), LDS cursors only ----
__global__ __launch_bounds__(1024) void part_scatter(const int* __restrict__ s0,
                                                     const int* __restrict__ d0,
                                                     const int* __restrict__ s1,
                                                     const int* __restrict__ d1,
                                                     const int* __restrict__ s2,
                                                     const int* __restrict__ d2,
                                                     const int* __restrict__ offs,
                                                     int* __restrict__ edges,
                                                     int E, int NB, int NCH, int M) {
    __shared__ int cur[NBMAX];
    const int chunk = blockIdx.x;
    const int rel   = blockIdx.y;
    const int* src = sel3(rel, s0, s1, s2);
    const int* dst = sel3(rel, d0, d1, d2);
    const int tid = threadIdx.x;
    const int* offs_r = offs + (size_t)rel * M;
    for (int b = tid; b < NB; b += 1024) cur[b] = offs_r[b * NCH + chunk];
    __syncthreads();
    int* edges_r = edges + (size_t)rel * E;
    const int base = chunk * EPB;
    const int end  = min(E, base + EPB);
    for (int i = base + tid; i < end; i += 1024) {
        int d = dst[i];
        int idx = atomicAdd(&cur[d >> 7], 1);   // LDS atomic, returns rank
        edges_r[idx] = (src[i] << 7) | (d & 127);
    }
}

// ---- per-bucket counting sort -> per-node CSR (srcs), off[g], rs_in[g] ----
__global__ __launch_bounds__(256) void bucket_csr(const int* __restrict__ edges,
                                                  const int* __restrict__ offs,
                                                  int* __restrict__ srcs,
                                                  int* __restrict__ off,
                                                  float* __restrict__ rs_in,
                                                  int N, int E, int NB, int NCH, int M) {
    __shared__ int hist[128];
    __shared__ int tmp[128];
    __shared__ int cur[128];
    const int tid = threadIdx.x;
    const int bkt = blockIdx.x;
    const int rel = blockIdx.y;
    const int* offs_r = offs + (size_t)rel * M;
    const int j0 = offs_r[bkt * NCH];
    const int j1 = (bkt == NB - 1) ? E : offs_r[(bkt + 1) * NCH];
    const int* edges_r = edges + (size_t)rel * E;
    int* srcs_r = srcs + (size_t)rel * E;

    if (tid < 128) hist[tid] = 0;
    __syncthreads();
    for (int j = j0 + tid; j < j1; j += 256) atomicAdd(&hist[edges_r[j] & 127], 1);
    __syncthreads();
    if (tid < 128) tmp[tid] = hist[tid];
    __syncthreads();
#pragma unroll
    for (int o = 1; o < 128; o <<= 1) {
        int t = (tid >= o && tid < 128) ? tmp[tid - o] : 0;
        __syncthreads();
        if (tid < 128) tmp[tid] += t;
        __syncthreads();
    }
    // tmp = inclusive; exclusive = tmp - hist
    if (tid < 128) {
        int excl = tmp[tid] - hist[tid];
        cur[tid] = j0 + excl;
        int node = bkt * 128 + tid;
        if (node < N) {
            size_t g = (size_t)rel * N + node;
            off[g]   = rel * E + j0 + excl;
            rs_in[g] = rsqrtf(fmaxf((float)hist[tid], 1.0f));
        }
    }
    __syncthreads();
    for (int j = j0 + tid; j < j1; j += 256) {
        int pk = edges_r[j];
        int pos = atomicAdd(&cur[pk & 127], 1);   // LDS atomic
        srcs_r[pos] = pk >> 7;
    }
}

// ---- y = rs_out[row] * (x @ W)  (fp32 compute, bf16 store) ----
__global__ __launch_bounds__(256) void gemm_kernel(const float* __restrict__ x,
                                                   const float* __restrict__ W,
                                                   const float* __restrict__ rs_out,
                                                   __hip_bfloat16* __restrict__ y, int nrows) {
    __shared__ float xs[BK * XS];
    __shared__ float ws[BK][D];

    const int tid = threadIdx.x;
    const int tx = tid & 31;
    const int ty = tid >> 5;
    const int row0 = blockIdx.x * BM;

    const int xr0 = tid >> 3;
    const int xk4 = tid & 7;
    const int wk0 = tid >> 5;
    const int wc4 = tid & 31;

    float acc[8][4];
#pragma unroll
    for (int i = 0; i < 8; ++i)
#pragma unroll
        for (int j = 0; j < 4; ++j) acc[i][j] = 0.f;

    float4 xv[2];
    float4 wv4[4];

#pragma unroll
    for (int l = 0; l < 2; ++l) {
        int grow = row0 + xr0 + l * 32;
        xv[l] = (grow < nrows) ? *(const float4*)(x + (size_t)grow * D + xk4 * 4)
                               : make_float4(0.f, 0.f, 0.f, 0.f);
    }
#pragma unroll
    for (int l = 0; l < 4; ++l)
        wv4[l] = *(const float4*)(W + (size_t)(wk0 + l * 8) * D + wc4 * 4);

    for (int kt = 0; kt < D; kt += BK) {
        __syncthreads();
#pragma unroll
        for (int l = 0; l < 2; ++l) {
            int r = xr0 + l * 32;
            xs[(xk4 * 4 + 0) * XS + r] = xv[l].x;
            xs[(xk4 * 4 + 1) * XS + r] = xv[l].y;
            xs[(xk4 * 4 + 2) * XS + r] = xv[l].z;
            xs[(xk4 * 4 + 3) * XS + r] = xv[l].w;
        }
#pragma unroll
        for (int l = 0; l < 4; ++l)
            *(float4*)&ws[wk0 + l * 8][wc4 * 4] = wv4[l];
        __syncthreads();
        if (kt + BK < D) {
            int ktn = kt + BK;
#pragma unroll
            for (int l = 0; l < 2; ++l) {
                int grow = row0 + xr0 + l * 32;
                xv[l] = (grow < nrows) ? *(const float4*)(x + (size_t)grow * D + ktn + xk4 * 4)
                                       : make_float4(0.f, 0.f, 0.f, 0.f);
            }
#pragma unroll
            for (int l = 0; l < 4; ++l)
                wv4[l] = *(const float4*)(W + (size_t)(ktn + wk0 + l * 8) * D + wc4 * 4);
        }
#pragma unroll
        for (int k = 0; k < BK; ++k) {
            float4 wv = *(const float4*)&ws[k][tx * 4];
            const float* xr = &xs[k * XS + ty * 8];
            float2 p0 = *(const float2*)(xr);
            float2 p1 = *(const float2*)(xr + 2);
            float2 p2 = *(const float2*)(xr + 4);
            float2 p3 = *(const float2*)(xr + 6);
            float xv8[8] = {p0.x, p0.y, p1.x, p1.y, p2.x, p2.y, p3.x, p3.y};
#pragma unroll
            for (int i = 0; i < 8; ++i) {
                acc[i][0] += xv8[i] * wv.x;
                acc[i][1] += xv8[i] * wv.y;
                acc[i][2] += xv8[i] * wv.z;
                acc[i][3] += xv8[i] * wv.w;
            }
        }
    }
#pragma unroll
    for (int i = 0; i < 8; ++i) {
        int grow = row0 + ty * 8 + i;
        if (grow < nrows) {
            float s = rs_out[grow];
            union { ushort4 u; __hip_bfloat16 h[4]; } pk;
            pk.h[0] = __float2bfloat16(acc[i][0] * s);
            pk.h[1] = __float2bfloat16(acc[i][1] * s);
            pk.h[2] = __float2bfloat16(acc[i][2] * s);
            pk.h[3] = __float2bfloat16(acc[i][3] * s);
            *(ushort4*)((unsigned short*)y + (size_t)grow * D + tx * 4) = pk.u;
        }
    }
}

// ---- gather-side aggregate: one 32-lane group per dst node (no atomics) ----
// y rows pre-scaled by rs_out. MODE 0: out = acc*ri  1: +=  2: relu(out+acc*ri+b)
template <int MODE>
__global__ __launch_bounds__(256) void agg_kernel(const unsigned short* __restrict__ y,
                                                  const int* __restrict__ srcs,
                                                  const int* __restrict__ off,
                                                  const float* __restrict__ rs_in,
                                                  const float* __restrict__ b0,
                                                  const float* __restrict__ b1,
                                                  const float* __restrict__ b2,
                                                  float* __restrict__ out,
                                                  int N, int rbase, int threeN, int Etot) {
    int gid  = blockIdx.x * blockDim.x + threadIdx.x;
    int node = gid >> 5;
    int lane = gid & 31;
    if (node >= N) return;
    int g = rbase + node;
    int j0 = off[g];
    int j1 = (g == threeN - 1) ? Etot : off[g + 1];

    float a0 = 0.f, a1 = 0.f, a2 = 0.f, a3 = 0.f;
    for (int j = j0; j < j1; ++j) {
        int s = srcs[j];
        ushort4 u = *(const ushort4*)(y + (size_t)s * D + lane * 4);
        a0 += bf2f(u.x);
        a1 += bf2f(u.y);
        a2 += bf2f(u.z);
        a3 += bf2f(u.w);
    }
    float ri = rs_in[g];
    float4 o = make_float4(a0 * ri, a1 * ri, a2 * ri, a3 * ri);
    float* orow = out + (size_t)node * D + lane * 4;
    if (MODE == 0) {
        *(float4*)orow = o;
    } else {
        float4 pv = *(const float4*)orow;
        o.x += pv.x; o.y += pv.y; o.z += pv.z; o.w += pv.w;
        if (MODE == 2) {
            int c0 = lane * 4;
            o.x = fmaxf(o.x + b0[c0 + 0] + b1[c0 + 0] + b2[c0 + 0], 0.f);
            o.y = fmaxf(o.y + b0[c0 + 1] + b1[c0 + 1] + b2[c0 + 1], 0.f);
            o.z = fmaxf(o.z + b0[c0 + 2] + b1[c0 + 2] + b2[c0 + 2], 0.f);
            o.w = fmaxf(o.w + b0[c0 + 3] + b1[c0 + 3] + b2[c0 + 3], 0.f);
        }
        *(float4*)orow = o;
    }
}

extern "C" void kernel_launch(void* const* d_in, const int* in_sizes, int n_in,
                              void* d_out, int out_size, void* d_ws, size_t ws_size,
                              hipStream_t stream) {
    const float* x = (const float*)d_in[0];
    const float* W[3]   = {(const float*)d_in[1], (const float*)d_in[5], (const float*)d_in[9]};
    const float* b[3]   = {(const float*)d_in[2], (const float*)d_in[6], (const float*)d_in[10]};
    const int*   src[3] = {(const int*)d_in[3],   (const int*)d_in[7],   (const int*)d_in[11]};
    const int*   dst[3] = {(const int*)d_in[4],   (const int*)d_in[8],   (const int*)d_in[12]};

    const int N = in_sizes[0] / D;
    const int E = in_sizes[3];
    const int threeN = 3 * N;
    const int Etot = 3 * E;
    float* out = (float*)d_out;

    const int NR     = (N + RNG - 1) / RNG;       // out-degree ranges (13)
    const int Npad   = NR * RNG;
    const int chunkE = (E + ODCH - 1) / ODCH;     // 150000
    const int NB     = (N + 127) >> 7;            // dst buckets (782)
    const int NCH    = (E + EPB - 1) / EPB;       // partition chunks (37)
    const int M      = NB * NCH;

    // ws: [rs_out 3N][rs_in 3N][off 3N][odscr 3*ODCH*Npad][offs 3M][edges 3E][srcs 3E][y N*D bf16] ~49 MB
    char* p = (char*)d_ws;
    auto align16 = [](char* q) { return (char*)(((uintptr_t)q + 15) & ~(uintptr_t)15); };
    float* rs_out = (float*)p;  p = align16(p + (size_t)threeN * 4);
    float* rs_in  = (float*)p;  p = align16(p + (size_t)threeN * 4);
    int*   off    = (int*)p;    p = align16(p + (size_t)threeN * 4);
    int*   odscr  = (int*)p;    p = align16(p + (size_t)3 * ODCH * Npad * 4);
    int*   offs   = (int*)p;    p = align16(p + (size_t)3 * M * 4);
    int*   edges  = (int*)p;    p = align16(p + (size_t)Etot * 4);
    int*   srcs   = (int*)p;    p = align16(p + (size_t)Etot * 4);
    unsigned short* y = (unsigned short*)p;

    // out-degree -> rs_out (no global atomics anywhere in this build)
    outdeg_hist<<<dim3(ODCH, NR, 3), 256, 0, stream>>>(src[0], src[1], src[2],
                                                       odscr, E, chunkE, Npad);
    outdeg_reduce<<<dim3((N + 255) / 256, 3), 256, 0, stream>>>(odscr, rs_out, N, Npad);

    // dst-bucket partition + per-bucket counting sort -> per-node CSR
    part_count<<<dim3(NCH, 3), 1024, 0, stream>>>(dst[0], dst[1], dst[2], offs, E, NB, NCH, M);
    part_scan<<<3, 1024, 0, stream>>>(offs, M);
    part_scatter<<<dim3(NCH, 3), 1024, 0, stream>>>(src[0], dst[0], src[1], dst[1],
                                                    src[2], dst[2], offs, edges, E, NB, NCH, M);
    bucket_csr<<<dim3(NB, 3), 256, 0, stream>>>(edges, offs, srcs, off, rs_in,
                                                N, E, NB, NCH, M);

    const int gblocks = (N + BM - 1) / BM;
    const int ablocks = (int)(((size_t)N * 32 + 255) / 256);
    for (int r = 0; r < 3; ++r) {
        gemm_kernel<<<gblocks, 256, 0, stream>>>(x, W[r], rs_out + (size_t)r * N,
                                                 (__hip_bfloat16*)y, N);
        if (r == 0)
            agg_kernel<0><<<ablocks, 256, 0, stream>>>(y, srcs, off, rs_in, b[0], b[1], b[2],
                                                       out, N, r * N, threeN, Etot);
        else if (r == 1)
            agg_kernel<1><<<ablocks, 256, 0, stream>>>(y, srcs, off, rs_in, b[0], b[1], b[2],
                                                       out, N, r * N, threeN, Etot);
        else
            agg_kernel<2><<<ablocks, 256, 0, stream>>>(y, srcs, off, rs_in, b[0], b[1], b[2],
                                                       out, N, r * N, threeN, Etot);
    }
}

// Round 7
// 579.357 us; speedup vs baseline: 3.6176x; 1.3316x over previous
//
#include <hip/hip_runtime.h>
#include <hip/hip_bf16.h>

#define D 128
#define BM 64
#define BK 32
#define XS 66        // padded LDS stride for transposed x tile (gemm)
#define RNG 16384    // nodes per out-degree range (packed 2x16-bit in 8192 ints = 32 KB LDS)
#define RSH 14       // log2(RNG)
#define ODCH 32      // out-degree edge chunks (grid = ODCH x NR x 3 = 672 blocks)
#define EPB 16384    // edges per partition block (1024 thr x 16)
#define NBMAX 1024   // max dst buckets (N <= 131072)

__device__ __forceinline__ float bf2f(unsigned short v) {
    union { unsigned int u; float f; } t;
    t.u = ((unsigned int)v) << 16;
    return t.f;
}

__device__ __forceinline__ const int* sel3(int r, const int* a, const int* b, const int* c) {
    return (r == 0) ? a : (r == 1) ? b : c;
}

// ---- out-degree: chunked LDS histograms, 2x16-bit packed counters, no global atomics ----
__global__ __launch_bounds__(256) void outdeg_hist(const int* __restrict__ s0,
                                                   const int* __restrict__ s1,
                                                   const int* __restrict__ s2,
                                                   unsigned int* __restrict__ scratch,
                                                   int E, int chunkE, int Wpad) {
    __shared__ unsigned int h[RNG / 2];   // 8192 ints = 32 KB
    const int chunk = blockIdx.x;   // 0..ODCH-1
    const int range = blockIdx.y;   // 0..NR-1
    const int rel   = blockIdx.z;
    const int* src = sel3(rel, s0, s1, s2);
    const int tid = threadIdx.x;
    for (int i = tid; i < RNG / 2; i += 256) h[i] = 0;
    __syncthreads();
    const int base = chunk * chunkE;
    const int end  = min(E, base + chunkE);
    for (int i = base + tid; i < end; i += 256) {
        int v = src[i];
        if ((v >> RSH) == range) {
            int local = v & (RNG - 1);
            atomicAdd(&h[local >> 1], 1u << ((local & 1) << 4));   // LDS atomic
        }
    }
    __syncthreads();
    unsigned int* dp = scratch + ((size_t)(rel * ODCH + chunk)) * Wpad
                     + ((size_t)range << (RSH - 1));
    for (int i = tid; i < RNG / 2; i += 256) dp[i] = h[i];
}

__global__ void outdeg_reduce(const unsigned int* __restrict__ scratch,
                              float* __restrict__ rs_out, int N, int Wpad) {
    int rel = blockIdx.y;
    int n = blockIdx.x * blockDim.x + threadIdx.x;
    if (n >= N) return;
    int word = n >> 1;
    int sh   = (n & 1) << 4;
    unsigned int s = 0;
#pragma unroll
    for (int c = 0; c < ODCH; ++c)
        s += (scratch[((size_t)(rel * ODCH + c)) * Wpad + word] >> sh) & 0xffffu;
    rs_out[(size_t)rel * N + n] = rsqrtf(fmaxf((float)s, 1.0f));
}

// ---- partition pass 1: per-(bucket,chunk) counts, non-atomic global writes ----
__global__ __launch_bounds__(1024) void part_count(const int* __restrict__ d0,
                                                   const int* __restrict__ d1,
                                                   const int* __restrict__ d2,
                                                   int* __restrict__ offs,
                                                   int E, int NB, int NCH, int M) {
    __shared__ int hist[NBMAX];
    const int chunk = blockIdx.x;
    const int rel   = blockIdx.y;
    const int* dst = sel3(rel, d0, d1, d2);
    const int tid = threadIdx.x;
    hist[tid] = 0;
    __syncthreads();
    const int base = chunk * EPB;
    const int end  = min(E, base + EPB);
    for (int i = base + tid; i < end; i += 1024)
        atomicAdd(&hist[dst[i] >> 7], 1);   // LDS atomic
    __syncthreads();
    int* offs_r = offs + (size_t)rel * M;
    for (int b = tid; b < NB; b += 1024) offs_r[b * NCH + chunk] = hist[b];
}

// ---- partition pass 2: exclusive scan over [bucket][chunk], one block per relation ----
__global__ __launch_bounds__(1024) void part_scan(int* __restrict__ offs, int M) {
    __shared__ int bs[1024];
    const int tid = threadIdx.x;
    int* a = offs + (size_t)blockIdx.x * M;
    const int PT = (M + 1023) >> 10;
    const int i0 = tid * PT;
    int s = 0;
    for (int j = 0; j < PT; ++j) {
        int idx = i0 + j;
        if (idx < M) s += a[idx];
    }
    bs[tid] = s;
    __syncthreads();
    for (int o = 1; o < 1024; o <<= 1) {
        int t = (tid >= o) ? bs[tid - o] : 0;
        __syncthreads();
        bs[tid] += t;
        __syncthreads();
    }
    int run = bs[tid] - s;
    for (int j = 0; j < PT; ++j) {
        int idx = i0 + j;
        if (idx < M) {
            int t = a[idx];
            a[idx] = run;
            run += t;
        }
    }
}

// ---- partition pass 3: scatter packed (src<<7)|(dst&127), LDS cursors only ----
__global__ __launch_bounds__(1024) void part_scatter(const int* __restrict__ s0,
                                                     const int* __restrict__ d0,
                                                     const int* __restrict__ s1,
                                                     const int* __restrict__ d1,
                                                     const int* __restrict__ s2,
                                                     const int* __restrict__ d2,
                                                     const int* __restrict__ offs,
                                                     int* __restrict__ edges,
                                                     int E, int NB, int NCH, int M) {
    __shared__ int cur[NBMAX];
    const int chunk = blockIdx.x;
    const int rel   = blockIdx.y;
    const int* src = sel3(rel, s0, s1, s2);
    const int* dst = sel3(rel, d0, d1, d2);
    const int tid = threadIdx.x;
    const int* offs_r = offs + (size_t)rel * M;
    for (int b = tid; b < NB; b += 1024) cur[b] = offs_r[b * NCH + chunk];
    __syncthreads();
    int* edges_r = edges + (size_t)rel * E;
    const int base = chunk * EPB;
    const int end  = min(E, base + EPB);
    for (int i = base + tid; i < end; i += 1024) {
        int d = dst[i];
        int idx = atomicAdd(&cur[d >> 7], 1);   // LDS atomic, returns rank
        edges_r[idx] = (src[i] << 7) | (d & 127);
    }
}

// ---- per-bucket counting sort -> per-node CSR (srcs), off[g], rs_in[g] ----
__global__ __launch_bounds__(256) void bucket_csr(const int* __restrict__ edges,
                                                  const int* __restrict__ offs,
                                                  int* __restrict__ srcs,
                                                  int* __restrict__ off,
                                                  float* __restrict__ rs_in,
                                                  int N, int E, int NB, int NCH, int M) {
    __shared__ int hist[128];
    __shared__ int tmp[128];
    __shared__ int cur[128];
    const int tid = threadIdx.x;
    const int bkt = blockIdx.x;
    const int rel = blockIdx.y;
    const int* offs_r = offs + (size_t)rel * M;
    const int j0 = offs_r[bkt * NCH];
    const int j1 = (bkt == NB - 1) ? E : offs_r[(bkt + 1) * NCH];
    const int* edges_r = edges + (size_t)rel * E;
    int* srcs_r = srcs + (size_t)rel * E;

    if (tid < 128) hist[tid] = 0;
    __syncthreads();
    for (int j = j0 + tid; j < j1; j += 256) atomicAdd(&hist[edges_r[j] & 127], 1);
    __syncthreads();
    if (tid < 128) tmp[tid] = hist[tid];
    __syncthreads();
#pragma unroll
    for (int o = 1; o < 128; o <<= 1) {
        int t = (tid >= o && tid < 128) ? tmp[tid - o] : 0;
        __syncthreads();
        if (tid < 128) tmp[tid] += t;
        __syncthreads();
    }
    if (tid < 128) {
        int excl = tmp[tid] - hist[tid];
        cur[tid] = j0 + excl;
        int node = bkt * 128 + tid;
        if (node < N) {
            size_t g = (size_t)rel * N + node;
            off[g]   = rel * E + j0 + excl;
            rs_in[g] = rsqrtf(fmaxf((float)hist[tid], 1.0f));
        }
    }
    __syncthreads();
    for (int j = j0 + tid; j < j1; j += 256) {
        int pk = edges_r[j];
        int pos = atomicAdd(&cur[pk & 127], 1);   // LDS atomic
        srcs_r[pos] = pk >> 7;
    }
}

// ---- y = rs_out[row] * (x @ W)  (fp32 compute, bf16 store) ----
__global__ __launch_bounds__(256) void gemm_kernel(const float* __restrict__ x,
                                                   const float* __restrict__ W,
                                                   const float* __restrict__ rs_out,
                                                   __hip_bfloat16* __restrict__ y, int nrows) {
    __shared__ float xs[BK * XS];
    __shared__ float ws[BK][D];

    const int tid = threadIdx.x;
    const int tx = tid & 31;
    const int ty = tid >> 5;
    const int row0 = blockIdx.x * BM;

    const int xr0 = tid >> 3;
    const int xk4 = tid & 7;
    const int wk0 = tid >> 5;
    const int wc4 = tid & 31;

    float acc[8][4];
#pragma unroll
    for (int i = 0; i < 8; ++i)
#pragma unroll
        for (int j = 0; j < 4; ++j) acc[i][j] = 0.f;

    float4 xv[2];
    float4 wv4[4];

#pragma unroll
    for (int l = 0; l < 2; ++l) {
        int grow = row0 + xr0 + l * 32;
        xv[l] = (grow < nrows) ? *(const float4*)(x + (size_t)grow * D + xk4 * 4)
                               : make_float4(0.f, 0.f, 0.f, 0.f);
    }
#pragma unroll
    for (int l = 0; l < 4; ++l)
        wv4[l] = *(const float4*)(W + (size_t)(wk0 + l * 8) * D + wc4 * 4);

    for (int kt = 0; kt < D; kt += BK) {
        __syncthreads();
#pragma unroll
        for (int l = 0; l < 2; ++l) {
            int r = xr0 + l * 32;
            xs[(xk4 * 4 + 0) * XS + r] = xv[l].x;
            xs[(xk4 * 4 + 1) * XS + r] = xv[l].y;
            xs[(xk4 * 4 + 2) * XS + r] = xv[l].z;
            xs[(xk4 * 4 + 3) * XS + r] = xv[l].w;
        }
#pragma unroll
        for (int l = 0; l < 4; ++l)
            *(float4*)&ws[wk0 + l * 8][wc4 * 4] = wv4[l];
        __syncthreads();
        if (kt + BK < D) {
            int ktn = kt + BK;
#pragma unroll
            for (int l = 0; l < 2; ++l) {
                int grow = row0 + xr0 + l * 32;
                xv[l] = (grow < nrows) ? *(const float4*)(x + (size_t)grow * D + ktn + xk4 * 4)
                                       : make_float4(0.f, 0.f, 0.f, 0.f);
            }
#pragma unroll
            for (int l = 0; l < 4; ++l)
                wv4[l] = *(const float4*)(W + (size_t)(ktn + wk0 + l * 8) * D + wc4 * 4);
        }
#pragma unroll
        for (int k = 0; k < BK; ++k) {
            float4 wv = *(const float4*)&ws[k][tx * 4];
            const float* xr = &xs[k * XS + ty * 8];
            float2 p0 = *(const float2*)(xr);
            float2 p1 = *(const float2*)(xr + 2);
            float2 p2 = *(const float2*)(xr + 4);
            float2 p3 = *(const float2*)(xr + 6);
            float xv8[8] = {p0.x, p0.y, p1.x, p1.y, p2.x, p2.y, p3.x, p3.y};
#pragma unroll
            for (int i = 0; i < 8; ++i) {
                acc[i][0] += xv8[i] * wv.x;
                acc[i][1] += xv8[i] * wv.y;
                acc[i][2] += xv8[i] * wv.z;
                acc[i][3] += xv8[i] * wv.w;
            }
        }
    }
#pragma unroll
    for (int i = 0; i < 8; ++i) {
        int grow = row0 + ty * 8 + i;
        if (grow < nrows) {
            float s = rs_out[grow];
            union { ushort4 u; __hip_bfloat16 h[4]; } pk;
            pk.h[0] = __float2bfloat16(acc[i][0] * s);
            pk.h[1] = __float2bfloat16(acc[i][1] * s);
            pk.h[2] = __float2bfloat16(acc[i][2] * s);
            pk.h[3] = __float2bfloat16(acc[i][3] * s);
            *(ushort4*)((unsigned short*)y + (size_t)grow * D + tx * 4) = pk.u;
        }
    }
}

// ---- gather-side aggregate: one 32-lane group per dst node (no atomics) ----
// y rows pre-scaled by rs_out. MODE 0: out = acc*ri  1: +=  2: relu(out+acc*ri+b)
template <int MODE>
__global__ __launch_bounds__(256) void agg_kernel(const unsigned short* __restrict__ y,
                                                  const int* __restrict__ srcs,
                                                  const int* __restrict__ off,
                                                  const float* __restrict__ rs_in,
                                                  const float* __restrict__ b0,
                                                  const float* __restrict__ b1,
                                                  const float* __restrict__ b2,
                                                  float* __restrict__ out,
                                                  int N, int rbase, int threeN, int Etot) {
    int gid  = blockIdx.x * blockDim.x + threadIdx.x;
    int node = gid >> 5;
    int lane = gid & 31;
    if (node >= N) return;
    int g = rbase + node;
    int j0 = off[g];
    int j1 = (g == threeN - 1) ? Etot : off[g + 1];

    float a0 = 0.f, a1 = 0.f, a2 = 0.f, a3 = 0.f;
    int j = j0;
    // unroll-2: two outstanding row gathers
    for (; j + 2 <= j1; j += 2) {
        int sA = srcs[j];
        int sB = srcs[j + 1];
        ushort4 uA = *(const ushort4*)(y + (size_t)sA * D + lane * 4);
        ushort4 uB = *(const ushort4*)(y + (size_t)sB * D + lane * 4);
        a0 += bf2f(uA.x) + bf2f(uB.x);
        a1 += bf2f(uA.y) + bf2f(uB.y);
        a2 += bf2f(uA.z) + bf2f(uB.z);
        a3 += bf2f(uA.w) + bf2f(uB.w);
    }
    if (j < j1) {
        int s = srcs[j];
        ushort4 u = *(const ushort4*)(y + (size_t)s * D + lane * 4);
        a0 += bf2f(u.x);
        a1 += bf2f(u.y);
        a2 += bf2f(u.z);
        a3 += bf2f(u.w);
    }
    float ri = rs_in[g];
    float4 o = make_float4(a0 * ri, a1 * ri, a2 * ri, a3 * ri);
    float* orow = out + (size_t)node * D + lane * 4;
    if (MODE == 0) {
        *(float4*)orow = o;
    } else {
        float4 pv = *(const float4*)orow;
        o.x += pv.x; o.y += pv.y; o.z += pv.z; o.w += pv.w;
        if (MODE == 2) {
            int c0 = lane * 4;
            o.x = fmaxf(o.x + b0[c0 + 0] + b1[c0 + 0] + b2[c0 + 0], 0.f);
            o.y = fmaxf(o.y + b0[c0 + 1] + b1[c0 + 1] + b2[c0 + 1], 0.f);
            o.z = fmaxf(o.z + b0[c0 + 2] + b1[c0 + 2] + b2[c0 + 2], 0.f);
            o.w = fmaxf(o.w + b0[c0 + 3] + b1[c0 + 3] + b2[c0 + 3], 0.f);
        }
        *(float4*)orow = o;
    }
}

extern "C" void kernel_launch(void* const* d_in, const int* in_sizes, int n_in,
                              void* d_out, int out_size, void* d_ws, size_t ws_size,
                              hipStream_t stream) {
    const float* x = (const float*)d_in[0];
    const float* W[3]   = {(const float*)d_in[1], (const float*)d_in[5], (const float*)d_in[9]};
    const float* b[3]   = {(const float*)d_in[2], (const float*)d_in[6], (const float*)d_in[10]};
    const int*   src[3] = {(const int*)d_in[3],   (const int*)d_in[7],   (const int*)d_in[11]};
    const int*   dst[3] = {(const int*)d_in[4],   (const int*)d_in[8],   (const int*)d_in[12]};

    const int N = in_sizes[0] / D;
    const int E = in_sizes[3];
    const int threeN = 3 * N;
    const int Etot = 3 * E;
    float* out = (float*)d_out;

    const int NR     = (N + RNG - 1) / RNG;       // out-degree ranges (7)
    const int Wpad   = NR * (RNG / 2);            // scratch ints per (rel,chunk)
    const int chunkE = (E + ODCH - 1) / ODCH;     // 18750
    const int NB     = (N + 127) >> 7;            // dst buckets (782)
    const int NCH    = (E + EPB - 1) / EPB;       // partition chunks (37)
    const int M      = NB * NCH;

    // ws: [rs_out 3N][rs_in 3N][off 3N][odscr 3*ODCH*Wpad u32 ~22MB][offs 3M][edges 3E][srcs 3E][y N*D bf16]
    char* p = (char*)d_ws;
    auto align16 = [](char* q) { return (char*)(((uintptr_t)q + 15) & ~(uintptr_t)15); };
    float* rs_out = (float*)p;          p = align16(p + (size_t)threeN * 4);
    float* rs_in  = (float*)p;          p = align16(p + (size_t)threeN * 4);
    int*   off    = (int*)p;            p = align16(p + (size_t)threeN * 4);
    unsigned int* odscr = (unsigned int*)p;  p = align16(p + (size_t)3 * ODCH * Wpad * 4);
    int*   offs   = (int*)p;            p = align16(p + (size_t)3 * M * 4);
    int*   edges  = (int*)p;            p = align16(p + (size_t)Etot * 4);
    int*   srcs   = (int*)p;            p = align16(p + (size_t)Etot * 4);
    unsigned short* y = (unsigned short*)p;

    // out-degree -> rs_out (no global atomics anywhere in this build)
    outdeg_hist<<<dim3(ODCH, NR, 3), 256, 0, stream>>>(src[0], src[1], src[2],
                                                       odscr, E, chunkE, Wpad);
    outdeg_reduce<<<dim3((N + 255) / 256, 3), 256, 0, stream>>>(odscr, rs_out, N, Wpad);

    // dst-bucket partition + per-bucket counting sort -> per-node CSR
    part_count<<<dim3(NCH, 3), 1024, 0, stream>>>(dst[0], dst[1], dst[2], offs, E, NB, NCH, M);
    part_scan<<<3, 1024, 0, stream>>>(offs, M);
    part_scatter<<<dim3(NCH, 3), 1024, 0, stream>>>(src[0], dst[0], src[1], dst[1],
                                                    src[2], dst[2], offs, edges, E, NB, NCH, M);
    bucket_csr<<<dim3(NB, 3), 256, 0, stream>>>(edges, offs, srcs, off, rs_in,
                                                N, E, NB, NCH, M);

    const int gblocks = (N + BM - 1) / BM;
    const int ablocks = (int)(((size_t)N * 32 + 255) / 256);
    for (int r = 0; r < 3; ++r) {
        gemm_kernel<<<gblocks, 256, 0, stream>>>(x, W[r], rs_out + (size_t)r * N,
                                                 (__hip_bfloat16*)y, N);
        if (r == 0)
            agg_kernel<0><<<ablocks, 256, 0, stream>>>(y, srcs, off, rs_in, b[0], b[1], b[2],
                                                       out, N, r * N, threeN, Etot);
        else if (r == 1)
            agg_kernel<1><<<ablocks, 256, 0, stream>>>(y, srcs, off, rs_in, b[0], b[1], b[2],
                                                       out, N, r * N, threeN, Etot);
        else
            agg_kernel<2><<<ablocks, 256, 0, stream>>>(y, srcs, off, rs_in, b[0], b[1], b[2],
                                                       out, N, r * N, threeN, Etot);
    }
}

// Round 9
// 463.167 us; speedup vs baseline: 4.5251x; 1.2509x over previous
//
#include <hip/hip_runtime.h>
#include <hip/hip_bf16.h>

#define D 128
#define RNG 16384    // nodes per out-degree range (packed 2x16-bit in 8192 ints = 32 KB LDS)
#define RSH 14       // log2(RNG)
#define ODCH 32      // out-degree edge chunks
#define EPB 16384    // edges per partition block (1024 thr x 16)
#define NBMAX 1024   // max dst buckets (N <= 131072)
#define GBM 64       // gemm rows per block
#define WTS 136      // padded bf16 stride (k) for LDS tiles: 272 B rows -> 2-way conflicts (free)

typedef short bfrag __attribute__((ext_vector_type(8)));   // 8 bf16 = 4 VGPRs (MFMA A/B)
typedef float ffrag __attribute__((ext_vector_type(4)));   // 4 fp32 (MFMA C/D)

__device__ __forceinline__ float bf2f(unsigned short v) {
    union { unsigned int u; float f; } t;
    t.u = ((unsigned int)v) << 16;
    return t.f;
}

__device__ __forceinline__ unsigned short f2bf(float f) {   // RNE, finite inputs
    union { float f; unsigned int u; } t;
    t.f = f;
    unsigned int r = t.u + 0x7fffu + ((t.u >> 16) & 1u);
    return (unsigned short)(r >> 16);
}

__device__ __forceinline__ const int* sel3(int r, const int* a, const int* b, const int* c) {
    return (r == 0) ? a : (r == 1) ? b : c;
}
__device__ __forceinline__ const float* sel3f(int r, const float* a, const float* b, const float* c) {
    return (r == 0) ? a : (r == 1) ? b : c;
}

// ---- out-degree: chunked LDS histograms, 2x16-bit packed counters, no global atomics ----
__global__ __launch_bounds__(256) void outdeg_hist(const int* __restrict__ s0,
                                                   const int* __restrict__ s1,
                                                   const int* __restrict__ s2,
                                                   unsigned int* __restrict__ scratch,
                                                   int E, int chunkE, int Wpad) {
    __shared__ unsigned int h[RNG / 2];
    const int chunk = blockIdx.x;
    const int range = blockIdx.y;
    const int rel   = blockIdx.z;
    const int* src = sel3(rel, s0, s1, s2);
    const int tid = threadIdx.x;
    for (int i = tid; i < RNG / 2; i += 256) h[i] = 0;
    __syncthreads();
    const int base = chunk * chunkE;
    const int end  = min(E, base + chunkE);
    for (int i = base + tid; i < end; i += 256) {
        int v = src[i];
        if ((v >> RSH) == range) {
            int local = v & (RNG - 1);
            atomicAdd(&h[local >> 1], 1u << ((local & 1) << 4));
        }
    }
    __syncthreads();
    unsigned int* dp = scratch + ((size_t)(rel * ODCH + chunk)) * Wpad
                     + ((size_t)range << (RSH - 1));
    for (int i = tid; i < RNG / 2; i += 256) dp[i] = h[i];
}

__global__ void outdeg_reduce(const unsigned int* __restrict__ scratch,
                              float* __restrict__ rs_out, int N, int Wpad) {
    int rel = blockIdx.y;
    int n = blockIdx.x * blockDim.x + threadIdx.x;
    if (n >= N) return;
    int word = n >> 1;
    int sh   = (n & 1) << 4;
    unsigned int s = 0;
#pragma unroll
    for (int c = 0; c < ODCH; ++c)
        s += (scratch[((size_t)(rel * ODCH + c)) * Wpad + word] >> sh) & 0xffffu;
    rs_out[(size_t)rel * N + n] = rsqrtf(fmaxf((float)s, 1.0f));
}

// ---- partition pass 1 ----
__global__ __launch_bounds__(1024) void part_count(const int* __restrict__ d0,
                                                   const int* __restrict__ d1,
                                                   const int* __restrict__ d2,
                                                   int* __restrict__ offs,
                                                   int E, int NB, int NCH, int M) {
    __shared__ int hist[NBMAX];
    const int chunk = blockIdx.x;
    const int rel   = blockIdx.y;
    const int* dst = sel3(rel, d0, d1, d2);
    const int tid = threadIdx.x;
    hist[tid] = 0;
    __syncthreads();
    const int base = chunk * EPB;
    const int end  = min(E, base + EPB);
    for (int i = base + tid; i < end; i += 1024)
        atomicAdd(&hist[dst[i] >> 7], 1);
    __syncthreads();
    int* offs_r = offs + (size_t)rel * M;
    for (int b = tid; b < NB; b += 1024) offs_r[b * NCH + chunk] = hist[b];
}

// ---- partition pass 2 ----
__global__ __launch_bounds__(1024) void part_scan(int* __restrict__ offs, int M) {
    __shared__ int bs[1024];
    const int tid = threadIdx.x;
    int* a = offs + (size_t)blockIdx.x * M;
    const int PT = (M + 1023) >> 10;
    const int i0 = tid * PT;
    int s = 0;
    for (int j = 0; j < PT; ++j) {
        int idx = i0 + j;
        if (idx < M) s += a[idx];
    }
    bs[tid] = s;
    __syncthreads();
    for (int o = 1; o < 1024; o <<= 1) {
        int t = (tid >= o) ? bs[tid - o] : 0;
        __syncthreads();
        bs[tid] += t;
        __syncthreads();
    }
    int run = bs[tid] - s;
    for (int j = 0; j < PT; ++j) {
        int idx = i0 + j;
        if (idx < M) {
            int t = a[idx];
            a[idx] = run;
            run += t;
        }
    }
}

// ---- partition pass 3 ----
__global__ __launch_bounds__(1024) void part_scatter(const int* __restrict__ s0,
                                                     const int* __restrict__ d0,
                                                     const int* __restrict__ s1,
                                                     const int* __restrict__ d1,
                                                     const int* __restrict__ s2,
                                                     const int* __restrict__ d2,
                                                     const int* __restrict__ offs,
                                                     int* __restrict__ edges,
                                                     int E, int NB, int NCH, int M) {
    __shared__ int cur[NBMAX];
    const int chunk = blockIdx.x;
    const int rel   = blockIdx.y;
    const int* src = sel3(rel, s0, s1, s2);
    const int* dst = sel3(rel, d0, d1, d2);
    const int tid = threadIdx.x;
    const int* offs_r = offs + (size_t)rel * M;
    for (int b = tid; b < NB; b += 1024) cur[b] = offs_r[b * NCH + chunk];
    __syncthreads();
    int* edges_r = edges + (size_t)rel * E;
    const int base = chunk * EPB;
    const int end  = min(E, base + EPB);
    for (int i = base + tid; i < end; i += 1024) {
        int d = dst[i];
        int idx = atomicAdd(&cur[d >> 7], 1);
        edges_r[idx] = (src[i] << 7) | (d & 127);
    }
}

// ---- per-bucket counting sort -> per-node CSR ----
__global__ __launch_bounds__(256) void bucket_csr(const int* __restrict__ edges,
                                                  const int* __restrict__ offs,
                                                  int* __restrict__ srcs,
                                                  int* __restrict__ off,
                                                  float* __restrict__ rs_in,
                                                  int N, int E, int NB, int NCH, int M) {
    __shared__ int hist[128];
    __shared__ int tmp[128];
    __shared__ int cur[128];
    const int tid = threadIdx.x;
    const int bkt = blockIdx.x;
    const int rel = blockIdx.y;
    const int* offs_r = offs + (size_t)rel * M;
    const int j0 = offs_r[bkt * NCH];
    const int j1 = (bkt == NB - 1) ? E : offs_r[(bkt + 1) * NCH];
    const int* edges_r = edges + (size_t)rel * E;
    int* srcs_r = srcs + (size_t)rel * E;

    if (tid < 128) hist[tid] = 0;
    __syncthreads();
    for (int j = j0 + tid; j < j1; j += 256) atomicAdd(&hist[edges_r[j] & 127], 1);
    __syncthreads();
    if (tid < 128) tmp[tid] = hist[tid];
    __syncthreads();
#pragma unroll
    for (int o = 1; o < 128; o <<= 1) {
        int t = (tid >= o && tid < 128) ? tmp[tid - o] : 0;
        __syncthreads();
        if (tid < 128) tmp[tid] += t;
        __syncthreads();
    }
    if (tid < 128) {
        int excl = tmp[tid] - hist[tid];
        cur[tid] = j0 + excl;
        int node = bkt * 128 + tid;
        if (node < N) {
            size_t g = (size_t)rel * N + node;
            off[g]   = rel * E + j0 + excl;
            rs_in[g] = rsqrtf(fmaxf((float)hist[tid], 1.0f));
        }
    }
    __syncthreads();
    for (int j = j0 + tid; j < j1; j += 256) {
        int pk = edges_r[j];
        int pos = atomicAdd(&cur[pk & 127], 1);
        srcs_r[pos] = pk >> 7;
    }
}

// ---- W (fp32 128x128) -> transposed bf16 wt[n][k], padded stride WTS ----
// 4096 float4s per relation -> grid.x = 16 (256 thr each). (R8 bug: grid.x=4 left
// wt rows k>=32 as workspace poison -> absmax 3.3.)
__global__ void wconv(const float* __restrict__ W0, const float* __restrict__ W1,
                      const float* __restrict__ W2, unsigned short* __restrict__ wtb) {
    const int rel = blockIdx.y;
    const float* W = sel3f(rel, W0, W1, W2);
    unsigned short* o = wtb + (size_t)rel * D * WTS;
    int t = blockIdx.x * 256 + threadIdx.x;    // 0..4095
    int k  = t >> 5;                           // 0..127
    int n0 = (t & 31) * 4;                     // 0..124
    float4 v = *(const float4*)(W + (size_t)k * D + n0);
    o[(n0 + 0) * WTS + k] = f2bf(v.x);
    o[(n0 + 1) * WTS + k] = f2bf(v.y);
    o[(n0 + 2) * WTS + k] = f2bf(v.z);
    o[(n0 + 3) * WTS + k] = f2bf(v.w);
}

// ---- y = rs_out[row] * (x @ W) via bf16 MFMA, bf16 store ----
// Layouts (m89-verified): A frag m=lane&15, k=quad*8+j ; B frag n=lane&15, same k ;
// C/D: col=lane&15, row=quad*4+reg.
__global__ __launch_bounds__(256) void gemm_mfma(const float* __restrict__ x,
                                                 const unsigned short* __restrict__ wtb,
                                                 const float* __restrict__ rs_out,
                                                 unsigned short* __restrict__ y, int nrows) {
    __shared__ __align__(16) unsigned short xs[GBM * WTS];   // 17408 B
    __shared__ __align__(16) unsigned short wt[D * WTS];     // 34816 B

    const int tid = threadIdx.x;
    const int row0 = blockIdx.x * GBM;

    // stage wt: already bf16+padded in global; linear copy 34816 B = 2176 float4
    {
        const float4* src4 = (const float4*)wtb;
        float4* dst4 = (float4*)wt;
        for (int i = tid; i < (D * WTS * 2) / 16; i += 256) dst4[i] = src4[i];
    }
    // stage xs: 64 rows x 128 k fp32 -> bf16 (2048 float4 loads, 8/thread)
#pragma unroll
    for (int i = 0; i < 8; ++i) {
        int idx = tid + i * 256;
        int row = idx >> 5;
        int k4  = (idx & 31) * 4;
        float4 v = make_float4(0.f, 0.f, 0.f, 0.f);
        if (row0 + row < nrows) v = *(const float4*)(x + (size_t)(row0 + row) * D + k4);
        ushort4 s;
        s.x = f2bf(v.x); s.y = f2bf(v.y); s.z = f2bf(v.z); s.w = f2bf(v.w);
        *(ushort4*)&xs[row * WTS + k4] = s;
    }
    __syncthreads();

    const int lane = tid & 63;
    const int wave = tid >> 6;
    const int m    = lane & 15;
    const int quad = lane >> 4;
    const int wrow = wave * 16;

    ffrag acc[8];
#pragma unroll
    for (int ct = 0; ct < 8; ++ct) acc[ct] = (ffrag){0.f, 0.f, 0.f, 0.f};

#pragma unroll
    for (int kc = 0; kc < 4; ++kc) {
        int k0 = kc * 32 + quad * 8;
        bfrag a = *(const bfrag*)&xs[(wrow + m) * WTS + k0];
#pragma unroll
        for (int ct = 0; ct < 8; ++ct) {
            bfrag b = *(const bfrag*)&wt[(ct * 16 + m) * WTS + k0];
            acc[ct] = __builtin_amdgcn_mfma_f32_16x16x32_bf16(a, b, acc[ct], 0, 0, 0);
        }
    }

    // epilogue: row = row0 + wrow + quad*4 + i, col = ct*16 + m
#pragma unroll
    for (int i = 0; i < 4; ++i) {
        int row = row0 + wrow + quad * 4 + i;
        if (row >= nrows) continue;
        float s = rs_out[row];
        unsigned short* yr = y + (size_t)row * D;
#pragma unroll
        for (int ct = 0; ct < 8; ++ct)
            yr[ct * 16 + m] = f2bf(acc[ct][i] * s);
    }
}

// ---- gather-side aggregate (unchanged) ----
template <int MODE>
__global__ __launch_bounds__(256) void agg_kernel(const unsigned short* __restrict__ y,
                                                  const int* __restrict__ srcs,
                                                  const int* __restrict__ off,
                                                  const float* __restrict__ rs_in,
                                                  const float* __restrict__ b0,
                                                  const float* __restrict__ b1,
                                                  const float* __restrict__ b2,
                                                  float* __restrict__ out,
                                                  int N, int rbase, int threeN, int Etot) {
    int gid  = blockIdx.x * blockDim.x + threadIdx.x;
    int node = gid >> 5;
    int lane = gid & 31;
    if (node >= N) return;
    int g = rbase + node;
    int j0 = off[g];
    int j1 = (g == threeN - 1) ? Etot : off[g + 1];

    float a0 = 0.f, a1 = 0.f, a2 = 0.f, a3 = 0.f;
    int j = j0;
    for (; j + 2 <= j1; j += 2) {
        int sA = srcs[j];
        int sB = srcs[j + 1];
        ushort4 uA = *(const ushort4*)(y + (size_t)sA * D + lane * 4);
        ushort4 uB = *(const ushort4*)(y + (size_t)sB * D + lane * 4);
        a0 += bf2f(uA.x) + bf2f(uB.x);
        a1 += bf2f(uA.y) + bf2f(uB.y);
        a2 += bf2f(uA.z) + bf2f(uB.z);
        a3 += bf2f(uA.w) + bf2f(uB.w);
    }
    if (j < j1) {
        int s = srcs[j];
        ushort4 u = *(const ushort4*)(y + (size_t)s * D + lane * 4);
        a0 += bf2f(u.x);
        a1 += bf2f(u.y);
        a2 += bf2f(u.z);
        a3 += bf2f(u.w);
    }
    float ri = rs_in[g];
    float4 o = make_float4(a0 * ri, a1 * ri, a2 * ri, a3 * ri);
    float* orow = out + (size_t)node * D + lane * 4;
    if (MODE == 0) {
        *(float4*)orow = o;
    } else {
        float4 pv = *(const float4*)orow;
        o.x += pv.x; o.y += pv.y; o.z += pv.z; o.w += pv.w;
        if (MODE == 2) {
            int c0 = lane * 4;
            o.x = fmaxf(o.x + b0[c0 + 0] + b1[c0 + 0] + b2[c0 + 0], 0.f);
            o.y = fmaxf(o.y + b0[c0 + 1] + b1[c0 + 1] + b2[c0 + 1], 0.f);
            o.z = fmaxf(o.z + b0[c0 + 2] + b1[c0 + 2] + b2[c0 + 2], 0.f);
            o.w = fmaxf(o.w + b0[c0 + 3] + b1[c0 + 3] + b2[c0 + 3], 0.f);
        }
        *(float4*)orow = o;
    }
}

extern "C" void kernel_launch(void* const* d_in, const int* in_sizes, int n_in,
                              void* d_out, int out_size, void* d_ws, size_t ws_size,
                              hipStream_t stream) {
    const float* x = (const float*)d_in[0];
    const float* W[3]   = {(const float*)d_in[1], (const float*)d_in[5], (const float*)d_in[9]};
    const float* b[3]   = {(const float*)d_in[2], (const float*)d_in[6], (const float*)d_in[10]};
    const int*   src[3] = {(const int*)d_in[3],   (const int*)d_in[7],   (const int*)d_in[11]};
    const int*   dst[3] = {(const int*)d_in[4],   (const int*)d_in[8],   (const int*)d_in[12]};

    const int N = in_sizes[0] / D;
    const int E = in_sizes[3];
    const int threeN = 3 * N;
    const int Etot = 3 * E;
    float* out = (float*)d_out;

    const int NR     = (N + RNG - 1) / RNG;
    const int Wpad   = NR * (RNG / 2);
    const int chunkE = (E + ODCH - 1) / ODCH;
    const int NB     = (N + 127) >> 7;
    const int NCH    = (E + EPB - 1) / EPB;
    const int M      = NB * NCH;

    char* p = (char*)d_ws;
    auto align16 = [](char* q) { return (char*)(((uintptr_t)q + 15) & ~(uintptr_t)15); };
    float* rs_out = (float*)p;          p = align16(p + (size_t)threeN * 4);
    float* rs_in  = (float*)p;          p = align16(p + (size_t)threeN * 4);
    int*   off    = (int*)p;            p = align16(p + (size_t)threeN * 4);
    unsigned int* odscr = (unsigned int*)p;  p = align16(p + (size_t)3 * ODCH * Wpad * 4);
    int*   offs   = (int*)p;            p = align16(p + (size_t)3 * M * 4);
    int*   edges  = (int*)p;            p = align16(p + (size_t)Etot * 4);
    int*   srcs   = (int*)p;            p = align16(p + (size_t)Etot * 4);
    unsigned short* wtb = (unsigned short*)p; p = align16(p + (size_t)3 * D * WTS * 2);
    unsigned short* y = (unsigned short*)p;

    // out-degree -> rs_out
    outdeg_hist<<<dim3(ODCH, NR, 3), 256, 0, stream>>>(src[0], src[1], src[2],
                                                       odscr, E, chunkE, Wpad);
    outdeg_reduce<<<dim3((N + 255) / 256, 3), 256, 0, stream>>>(odscr, rs_out, N, Wpad);

    // dst-bucket partition + per-bucket counting sort -> per-node CSR
    part_count<<<dim3(NCH, 3), 1024, 0, stream>>>(dst[0], dst[1], dst[2], offs, E, NB, NCH, M);
    part_scan<<<3, 1024, 0, stream>>>(offs, M);
    part_scatter<<<dim3(NCH, 3), 1024, 0, stream>>>(src[0], dst[0], src[1], dst[1],
                                                    src[2], dst[2], offs, edges, E, NB, NCH, M);
    bucket_csr<<<dim3(NB, 3), 256, 0, stream>>>(edges, offs, srcs, off, rs_in,
                                                N, E, NB, NCH, M);

    // W -> transposed bf16 (one-time): 4096 float4s -> 16 blocks x 256
    wconv<<<dim3(16, 3), 256, 0, stream>>>(W[0], W[1], W[2], wtb);

    const int gblocks = (N + GBM - 1) / GBM;
    const int ablocks = (int)(((size_t)N * 32 + 255) / 256);
    for (int r = 0; r < 3; ++r) {
        gemm_mfma<<<gblocks, 256, 0, stream>>>(x, wtb + (size_t)r * D * WTS,
                                               rs_out + (size_t)r * N, y, N);
        if (r == 0)
            agg_kernel<0><<<ablocks, 256, 0, stream>>>(y, srcs, off, rs_in, b[0], b[1], b[2],
                                                       out, N, r * N, threeN, Etot);
        else if (r == 1)
            agg_kernel<1><<<ablocks, 256, 0, stream>>>(y, srcs, off, rs_in, b[0], b[1], b[2],
                                                       out, N, r * N, threeN, Etot);
        else
            agg_kernel<2><<<ablocks, 256, 0, stream>>>(y, srcs, off, rs_in, b[0], b[1], b[2],
                                                       out, N, r * N, threeN, Etot);
    }
}